// Round 23
// baseline (662.487 us; speedup 1.0000x reference)
//
#include <hip/hip_runtime.h>
#include <hip/hip_bf16.h>

#define SEQ 2048
#define DM  1024
#define DI  2048
#define DST 16
#define DTR 64
#define NVOC 32000
#define NVOCP 32768   // padded N for lm_head 256-tile grid
#define NIN  6272     // logical fused in_proj N: 4096 (x,res) + 128 (xdbl) + 2048 (delta)
#define NINP 6400     // padded to 25 tiles of 256
#define NC  64    // scan chunks
#define LC  32    // chunk length; NC*LC == SEQ
#define LOG2E 1.4426950408889634f

typedef __bf16 bf16x8 __attribute__((ext_vector_type(8)));
typedef float  f32x4  __attribute__((ext_vector_type(4)));

__device__ __forceinline__ float fexp(float x) { return __expf(x); }                  // mul+v_exp
__device__ __forceinline__ float fexp2(float x) { return __builtin_amdgcn_exp2f(x); } // raw v_exp_f32
__device__ __forceinline__ float siluf(float x) { return x / (1.f + fexp(-x)); }
__device__ __forceinline__ float softplusf(float x) {
    return fmaxf(x, 0.f) + log1pf(fexp(-fabsf(x)));
}
__device__ __forceinline__ unsigned short f2bf(float f) {
    union { __hip_bfloat16 h; unsigned short u; } c;
    c.h = __float2bfloat16(f);
    return c.u;
}

// rmsnorm with optional embed-gather input (ids!=null: x := embed[ids[l]], also writes h).
__global__ void rmsnorm_kernel(const float* __restrict__ x, const float* __restrict__ w,
                               float* __restrict__ o, unsigned short* __restrict__ ob,
                               const int* __restrict__ ids, const float* __restrict__ embed,
                               float* __restrict__ hout) {
    int l = blockIdx.x;
    int t = threadIdx.x; // 256
    float4 v;
    if (ids) {
        int row = ids[l];
        v = ((const float4*)(embed + (size_t)row * DM))[t];
        ((float4*)(hout + (size_t)l * DM))[t] = v;   // h = gathered row (residual base)
    } else {
        v = ((const float4*)(x + (size_t)l * DM))[t];
    }
    float ss = v.x*v.x + v.y*v.y + v.z*v.z + v.w*v.w;
    #pragma unroll
    for (int m = 32; m; m >>= 1) ss += __shfl_xor(ss, m);
    __shared__ float red[4];
    if ((t & 63) == 0) red[t >> 6] = ss;
    __syncthreads();
    float tot = red[0] + red[1] + red[2] + red[3];
    float sc = rsqrtf(tot * (1.f / DM) + 1e-6f);
    float4 wv = ((const float4*)w)[t];
    float4 ov;
    ov.x = v.x * sc * wv.x;
    ov.y = v.y * sc * wv.y;
    ov.z = v.z * sc * wv.z;
    ov.w = v.w * sc * wv.w;
    if (ob) {
        uint2 pk;
        pk.x = (unsigned)f2bf(ov.x) | ((unsigned)f2bf(ov.y) << 16);
        pk.y = (unsigned)f2bf(ov.z) | ((unsigned)f2bf(ov.w) << 16);
        ((uint2*)(ob + (size_t)l * DM))[t] = pk;
    } else {
        ((float4*)(o + (size_t)l * DM))[t] = ov;
    }
}

// ===== single fused transpose, 64x64 tiles: f32 [K][N] -> bf16 [Npad][K] =====
__global__ void transpose_all(const float* __restrict__ in_w, const float* __restrict__ xp_w,
                              const float* __restrict__ out_w,
                              const float* __restrict__ lm_w,
                              unsigned short* __restrict__ in_wT, unsigned short* __restrict__ out_wT,
                              unsigned short* __restrict__ lm_wT) {
    int b = blockIdx.x;
    const float* W; unsigned short* WT; int K, N, Np, loc;
    if      (b < 1024)  { W = in_w;                        WT = in_wT;                                              K=1024; N=4096;  Np=4096;  loc = b; }
    else if (b < 1056)  { W = xp_w;                        WT = in_wT + (size_t)4096 * 1024;                        K=1024; N=96;    Np=128;   loc = b - 1024; }
    else if (b < 2080)  { W = in_w + (size_t)1024 * 4096;  WT = in_wT + (size_t)NINP * 1024;                        K=1024; N=4096;  Np=4096;  loc = b - 1056; }
    else if (b < 2112)  { W = xp_w + (size_t)1024 * 96;    WT = in_wT + (size_t)NINP * 1024 + (size_t)4096 * 1024;  K=1024; N=96;    Np=128;   loc = b - 2080; }
    else if (b < 2624)  { W = out_w;                       WT = out_wT;                                             K=2048; N=1024;  Np=1024;  loc = b - 2112; }
    else if (b < 3136)  { W = out_w + (size_t)2048 * 1024; WT = out_wT + (size_t)1024 * 2048;                       K=2048; N=1024;  Np=1024;  loc = b - 2624; }
    else                { if (!lm_wT) return; W = lm_w;    WT = lm_wT;                                              K=1024; N=32000; Np=32768; loc = b - 3136; }
    int tiles_x = Np >> 6;
    int n0 = (loc % tiles_x) * 64, k0 = (loc / tiles_x) * 64;
    __shared__ float tile[64][65];   // [n][k]
    int t = threadIdx.y * 32 + threadIdx.x;   // 0..255
    {
        int kk = t >> 4;            // 0..15
        int n4 = (t & 15) * 4;      // 0..60
        #pragma unroll
        for (int i = 0; i < 4; i++) {
            int k = kk + i * 16;
            int n = n0 + n4;
            float4 v;
            if (n < N) v = *(const float4*)&W[(size_t)(k0 + k) * N + n];
            else       v = make_float4(0.f, 0.f, 0.f, 0.f);
            tile[n4 + 0][k] = v.x;
            tile[n4 + 1][k] = v.y;
            tile[n4 + 2][k] = v.z;
            tile[n4 + 3][k] = v.w;
        }
    }
    __syncthreads();
    {
        int nr = t >> 3;            // 0..31
        int u  = t & 7;             // k-group: 8 bf16 each
        #pragma unroll
        for (int pass = 0; pass < 2; pass++) {
            int nn = pass * 32 + nr;
            unsigned short tmp[8];
            #pragma unroll
            for (int j = 0; j < 8; j++) tmp[j] = f2bf(tile[nn][u * 8 + j]);
            uint4 pk;
            pk.x = (unsigned)tmp[0] | ((unsigned)tmp[1] << 16);
            pk.y = (unsigned)tmp[2] | ((unsigned)tmp[3] << 16);
            pk.z = (unsigned)tmp[4] | ((unsigned)tmp[5] << 16);
            pk.w = (unsigned)tmp[6] | ((unsigned)tmp[7] << 16);
            *(uint4*)&WT[(size_t)(n0 + nn) * K + k0 + u * 8] = pk;
        }
    }
}

// ===== compose W_effT = (xp_w[:, :64] @ dt_w)^T, bf16 [2048][1024], fp32 math =====
__global__ __launch_bounds__(256) void compose_dtw(const float* __restrict__ xp_w,
                                                   const float* __restrict__ dt_w,
                                                   unsigned short* __restrict__ in_wT) {
    int n0 = blockIdx.x * 64, k0 = blockIdx.y * 64, L = blockIdx.z;
    const float* xp = xp_w + (size_t)L * DM * 96;
    const float* dw = dt_w + (size_t)L * DTR * DI;
    unsigned short* WT = in_wT + (size_t)L * NINP * 1024 + (size_t)4224 * 1024;
    __shared__ float xps[64][65];   // [k][r]
    __shared__ float dts[64][65];   // [r][n]
    int t = threadIdx.x;
    for (int i = t; i < 64 * 64; i += 256) {
        int row = i >> 6, col = i & 63;
        xps[row][col] = xp[(size_t)(k0 + row) * 96 + col];       // r = col < 64
        dts[row][col] = dw[(size_t)row * DI + n0 + col];
    }
    __syncthreads();
    int n = t & 63, kg = t >> 6;    // 4 k-groups of 16
    float acc[16] = {};
    for (int r = 0; r < 64; r++) {
        float d = dts[r][n];
        #pragma unroll
        for (int k = 0; k < 16; k++)
            acc[k] += xps[kg * 16 + k][r] * d;
    }
    #pragma unroll
    for (int k = 0; k < 16; k++)
        WT[(size_t)(n0 + n) * 1024 + k0 + kg * 16 + k] = f2bf(acc[k]);
}

// Generic fp32 GEMM (fallback only)
template<int ACT>
__global__ __launch_bounds__(256) void gemm_f32(const float* __restrict__ A, int lda,
                                                const float* __restrict__ B,
                                                const float* __restrict__ bias,
                                                const float* __restrict__ add,
                                                float* __restrict__ C,
                                                int M, int N, int K) {
    __shared__ float As[16][68];
    __shared__ float Bs[16][64];
    int tx = threadIdx.x, ty = threadIdx.y;
    int t = ty * 16 + tx;
    int m0 = blockIdx.y * 64, n0 = blockIdx.x * 64;
    float acc[4][4] = {};
    for (int k0 = 0; k0 < K; k0 += 16) {
        #pragma unroll
        for (int i = 0; i < 4; i++) {
            int idx = t + i * 256;
            int mm = idx >> 4, kk = idx & 15;
            As[kk][mm] = A[(size_t)(m0 + mm) * lda + k0 + kk];
            int nn = idx & 63, k2 = idx >> 6;
            Bs[k2][nn] = B[(size_t)(k0 + k2) * N + n0 + nn];
        }
        __syncthreads();
        #pragma unroll
        for (int kk = 0; kk < 16; kk++) {
            float4 a = *(const float4*)&As[kk][ty * 4];
            float4 b = *(const float4*)&Bs[kk][tx * 4];
            acc[0][0] += a.x*b.x; acc[0][1] += a.x*b.y; acc[0][2] += a.x*b.z; acc[0][3] += a.x*b.w;
            acc[1][0] += a.y*b.x; acc[1][1] += a.y*b.y; acc[1][2] += a.y*b.z; acc[1][3] += a.y*b.w;
            acc[2][0] += a.z*b.x; acc[2][1] += a.z*b.y; acc[2][2] += a.z*b.z; acc[2][3] += a.z*b.w;
            acc[3][0] += a.w*b.x; acc[3][1] += a.w*b.y; acc[3][2] += a.w*b.z; acc[3][3] += a.w*b.w;
        }
        __syncthreads();
    }
    #pragma unroll
    for (int i = 0; i < 4; i++) {
        int row = m0 + ty * 4 + i;
        float4 r;
        float* pr = &r.x;
        #pragma unroll
        for (int j = 0; j < 4; j++) {
            int col = n0 + tx * 4 + j;
            float v = acc[i][j];
            if (bias) v += bias[col];
            if (add)  v += add[(size_t)row * N + col];
            if (ACT == 1) v = softplusf(v);
            pr[j] = v;
        }
        *(float4*)&C[(size_t)row * N + n0 + tx * 4] = r;
    }
}

// bf16 MFMA GEMM (m97 structure): 128x128 tile, BK=32. Used for out_proj.
template<int BIAS, int ADD, int ACT>
__global__ __launch_bounds__(256) void gemm_bf16(const unsigned short* __restrict__ A, int lda,
                                                 const unsigned short* __restrict__ BT,
                                                 const float* __restrict__ bias,
                                                 const float* __restrict__ add,
                                                 float* __restrict__ C,
                                                 int M, int N, int K) {
    __shared__ unsigned short As[128 * 32];
    __shared__ unsigned short Bs[128 * 32];
    int t = threadIdx.x;
    int w = t >> 6, l = t & 63;
    int wm = w >> 1, wn = w & 1;
    int m0 = blockIdx.x * 128;
    int n0 = blockIdx.y * 128;
    int lr = l & 15, lk = (l >> 4) * 8;
    int sr = t >> 2, sc = (t & 3) * 8;     // staging: row, k-offset
    f32x4 acc[4][4] = {};
    for (int k0 = 0; k0 < K; k0 += 32) {
        const unsigned short* ga = A  + (size_t)(m0 + sr) * lda + k0 + sc;
        const unsigned short* gb = BT + (size_t)(n0 + sr) * K + k0 + sc;
        unsigned short* la = As + w * 512;   // wave-uniform base; HW adds lane*16B
        unsigned short* lb = Bs + w * 512;
        __builtin_amdgcn_global_load_lds((const __attribute__((address_space(1))) void*)ga,
            (__attribute__((address_space(3))) void*)la, 16, 0, 0);
        __builtin_amdgcn_global_load_lds((const __attribute__((address_space(1))) void*)(ga + (size_t)64 * lda),
            (__attribute__((address_space(3))) void*)(la + 2048), 16, 0, 0);
        __builtin_amdgcn_global_load_lds((const __attribute__((address_space(1))) void*)gb,
            (__attribute__((address_space(3))) void*)(lb), 16, 0, 0);
        __builtin_amdgcn_global_load_lds((const __attribute__((address_space(1))) void*)(gb + (size_t)64 * K),
            (__attribute__((address_space(3))) void*)(lb + 2048), 16, 0, 0);
        __syncthreads();
        bf16x8 af[4], bfr[4];
        #pragma unroll
        for (int i = 0; i < 4; i++) {
            af[i]  = *reinterpret_cast<const bf16x8*>(&As[(wm * 64 + i * 16 + lr) * 32 + lk]);
            bfr[i] = *reinterpret_cast<const bf16x8*>(&Bs[(wn * 64 + i * 16 + lr) * 32 + lk]);
        }
        #pragma unroll
        for (int i = 0; i < 4; i++)
            #pragma unroll
            for (int j = 0; j < 4; j++)
                acc[i][j] = __builtin_amdgcn_mfma_f32_16x16x32_bf16(af[i], bfr[j], acc[i][j], 0, 0, 0);
        __syncthreads();
    }
    int cr = (l >> 4) * 4;
    #pragma unroll
    for (int i = 0; i < 4; i++) {
        #pragma unroll
        for (int j = 0; j < 4; j++) {
            int col = n0 + wn * 64 + j * 16 + lr;
            float bv = BIAS ? bias[col] : 0.f;
            #pragma unroll
            for (int rr = 0; rr < 4; rr++) {
                int row = m0 + wm * 64 + i * 16 + cr + rr;
                float v = acc[i][j][rr] + bv;
                if (ADD) v += add[(size_t)row * N + col];
                if (ACT == 1) v = softplusf(v);
                C[(size_t)row * N + col] = v;
            }
        }
    }
}

// ==== 256x256 3-buf counted-vmcnt GEMM body ====
template<int EPI>
__global__ __launch_bounds__(1024, 4) void gemm_256(
        const unsigned short* __restrict__ A,
        const unsigned short* __restrict__ BT,
        float* __restrict__ C, const float* __restrict__ bias,
        float* __restrict__ xp_out, float* __restrict__ dout,
        const float* __restrict__ dt_bias,
        int M, int N, int K) {
    extern __shared__ unsigned short lds[];   // 3 x 16384 shorts (A|B per buf)
    const int t = threadIdx.x;
    const int w = t >> 6, l = t & 63;
    const int wr = w >> 2, wc = w & 3;        // 4x4 waves, 64x64 tile each
    int bxx = blockIdx.x, byy = blockIdx.y;
    if (gridDim.x == 8 && (gridDim.y & 7) == 0) {
        int lin = blockIdx.y * 8 + blockIdx.x;
        int xcd = lin & 7, i = lin >> 3;
        bxx = i & 7;
        byy = xcd * (gridDim.y >> 3) + (i >> 3);
    }
    const int m0 = bxx * 256, n0 = byy * 256;
    const int lr = l & 15;
    const int rowA = wr * 64 + lr;
    const int rowB = wc * 64 + lr;
    const int colR = (((l >> 4) ^ (lr & 3)) * 8);   // swizzled ds_read col (shorts)
    const int srow = t >> 2;                        // staging row 0..255
    const int scol = (((t & 3) ^ (srow & 3)) * 8);  // pre-swizzled global col
    const int NT = K >> 5;                          // BK=32
    f32x4 acc[4][4] = {};
    bf16x8 af[4], bf[4];

    const unsigned short* gA = A  + (size_t)(m0 + srow) * K + scol;
    const unsigned short* gB = BT + (size_t)(n0 + srow) * K + scol;

    #pragma unroll
    for (int pp = 0; pp < 2; pp++) {
        if (pp < NT) {
            unsigned short* Ld = lds + pp * 16384;
            __builtin_amdgcn_global_load_lds(
                (const __attribute__((address_space(1))) void*)(gA + pp * 32),
                (__attribute__((address_space(3))) void*)(Ld + w * 512), 16, 0, 0);
            __builtin_amdgcn_global_load_lds(
                (const __attribute__((address_space(1))) void*)(gB + pp * 32),
                (__attribute__((address_space(3))) void*)(Ld + 8192 + w * 512), 16, 0, 0);
        }
    }

    for (int kt = 0; kt < NT; kt++) {
        if (kt >= NT - 2) { asm volatile("s_waitcnt vmcnt(0)" ::: "memory"); }
        else              { asm volatile("s_waitcnt vmcnt(2)" ::: "memory"); }
        __builtin_amdgcn_sched_barrier(0);
        __builtin_amdgcn_s_barrier();
        __builtin_amdgcn_sched_barrier(0);
        const unsigned short* Ab = lds + (kt % 3) * 16384;
        const unsigned short* Bb = Ab + 8192;
        #pragma unroll
        for (int i = 0; i < 4; i++)
            af[i] = *reinterpret_cast<const bf16x8*>(&Ab[(rowA + i * 16) * 32 + colR]);
        #pragma unroll
        for (int j = 0; j < 4; j++)
            bf[j] = *reinterpret_cast<const bf16x8*>(&Bb[(rowB + j * 16) * 32 + colR]);
        if (kt + 2 < NT) {
            unsigned short* Ld = lds + ((kt + 2) % 3) * 16384;
            __builtin_amdgcn_global_load_lds(
                (const __attribute__((address_space(1))) void*)(gA + (kt + 2) * 32),
                (__attribute__((address_space(3))) void*)(Ld + w * 512), 16, 0, 0);
            __builtin_amdgcn_global_load_lds(
                (const __attribute__((address_space(1))) void*)(gB + (kt + 2) * 32),
                (__attribute__((address_space(3))) void*)(Ld + 8192 + w * 512), 16, 0, 0);
        }
        __builtin_amdgcn_s_setprio(1);
        #pragma unroll
        for (int i = 0; i < 4; i++)
            #pragma unroll
            for (int j = 0; j < 4; j++)
                acc[i][j] = __builtin_amdgcn_mfma_f32_16x16x32_bf16(af[i], bf[j], acc[i][j], 0, 0, 0);
        __builtin_amdgcn_s_setprio(0);
    }

    // ---- epilogue: LDS transpose -> f32x4 coalesced stores ----
    float* cf = (float*)lds;   // [64][260] f32 = 66.6 KB (fits 96 KB dyn-LDS)
    const int cr = (l >> 4) * 4;
    for (int r = 0; r < 4; r++) {
        __syncthreads();   // previous round's reads complete before overwrite
        if (wr == r) {
            #pragma unroll
            for (int i = 0; i < 4; i++)
                #pragma unroll
                for (int j = 0; j < 4; j++) {
                    int col = wc * 64 + j * 16 + lr;
                    #pragma unroll
                    for (int rr = 0; rr < 4; rr++)
                        cf[(i * 16 + cr + rr) * 260 + col] = acc[i][j][rr];
                }
        }
        __syncthreads();
        #pragma unroll
        for (int pass = 0; pass < 4; pass++) {
            int row = pass * 16 + (t >> 6);
            int f4 = t & 63;
            f32x4 v = *(const f32x4*)&cf[row * 260 + f4 * 4];
            int grow = m0 + r * 64 + row;
            int gcol = n0 + f4 * 4;
            if (EPI == 0) {
                if (gcol < N)
                    __builtin_nontemporal_store(v, (f32x4*)&C[(size_t)grow * N + gcol]);
            } else {
                if (gcol < 4096) {
                    const f32x4 bv = *(const f32x4*)&bias[gcol];
                    v += bv;
                    *(f32x4*)&C[(size_t)grow * 4096 + gcol] = v;
                } else if (gcol < 4224) {
                    *(f32x4*)&xp_out[(size_t)grow * 128 + (gcol - 4096)] = v;
                } else if (gcol < NIN) {
                    int c2 = gcol - 4224;
                    const f32x4 bv = *(const f32x4*)&dt_bias[c2];
                    f32x4 o;
                    o[0] = softplusf(v[0] + bv[0]);
                    o[1] = softplusf(v[1] + bv[1]);
                    o[2] = softplusf(v[2] + bv[2]);
                    o[3] = softplusf(v[3] + bv[3]);
                    *(f32x4*)&dout[(size_t)grow * DI + c2] = o;
                }
            }
        }
    }
}

// fallback xproj (fp32, stride-128 output)
__global__ void xproj_kernel(const float* __restrict__ u, const float* __restrict__ xw,
                             float* __restrict__ xdbl) {
    int l0 = blockIdx.x * 4;
    int t = threadIdx.x; // 128
    __shared__ float us[4][DM];
    for (int i = t; i < 4 * DM; i += 128) us[i >> 10][i & 1023] = u[(size_t)l0 * DM + i];
    __syncthreads();
    if (t < 96) {
        float a0 = 0.f, a1 = 0.f, a2 = 0.f, a3 = 0.f;
        for (int k = 0; k < DM; k++) {
            float wv = xw[(size_t)k * 96 + t];
            a0 += us[0][k] * wv; a1 += us[1][k] * wv;
            a2 += us[2][k] * wv; a3 += us[3][k] * wv;
        }
        xdbl[(size_t)(l0 + 0) * 128 + t] = a0;
        xdbl[(size_t)(l0 + 1) * 128 + t] = a1;
        xdbl[(size_t)(l0 + 2) * 128 + t] = a2;
        xdbl[(size_t)(l0 + 3) * 128 + t] = a3;
    }
}

// ---- chunked selective scan with fused conv+silu (x = silu(conv(xr))) ----
// a[n] = -exp(A_log)*log2(e): state decay = exp2(dv*a[n]) via raw v_exp_f32.
__global__ __launch_bounds__(256) void scan_p1(const float* __restrict__ xr,
        const float* __restrict__ delta, const float* __restrict__ xdbl,
        const float* __restrict__ cw, const float* __restrict__ cb,
        const float* __restrict__ A_log, float* __restrict__ P, float* __restrict__ S) {
    int c = blockIdx.x;
    int d = blockIdx.y * 256 + threadIdx.x;
    int l0 = c * LC;
    __shared__ float Bsh[LC][16];
    __shared__ float cwsh[4][LC];
    __shared__ float cbsh[LC];
    {
        int t = threadIdx.x;
        #pragma unroll
        for (int i = t; i < LC * 16; i += 256) {
            int ll = i >> 4, q = i & 15;
            Bsh[ll][q] = xdbl[(size_t)(l0 + ll) * 128 + 64 + q];
        }
        if (t < LC) {
            cbsh[t] = cb[l0 + t];
            #pragma unroll
            for (int k = 0; k < 4; k++) cwsh[k][t] = cw[k * SEQ + l0 + t];
        }
    }
    __syncthreads();
    float a[16];
    #pragma unroll
    for (int i = 0; i < 4; i++) {
        float4 al = ((const float4*)(A_log + (size_t)d * 16))[i];
        a[4*i+0] = -fexp(al.x) * LOG2E; a[4*i+1] = -fexp(al.y) * LOG2E;
        a[4*i+2] = -fexp(al.z) * LOG2E; a[4*i+3] = -fexp(al.w) * LOG2E;
    }
    float s[16] = {};
    float sumdv = 0.f;
    for (int ll = 0; ll < LC; ll++) {
        size_t lrow = (size_t)(l0 + ll);
        float dv = delta[lrow * DI + d];
        const float* xrow = xr + lrow * 4096;
        float accv = cbsh[ll];
        #pragma unroll
        for (int k = 0; k < 4; k++) {
            int cc = d + k - 1;
            if (cc >= 0 && cc < DI) accv += xrow[cc] * cwsh[k][ll];
        }
        float xv = siluf(accv);
        float du = dv * xv;
        sumdv += dv;
        #pragma unroll
        for (int n = 0; n < 16; n++)
            s[n] = fexp2(dv * a[n]) * s[n] + du * Bsh[ll][n];
    }
    size_t o = ((size_t)c * DI + d) * 16;
    #pragma unroll
    for (int i = 0; i < 4; i++) {
        float4 sv = make_float4(s[4*i], s[4*i+1], s[4*i+2], s[4*i+3]);
        float4 pv = make_float4(fexp2(a[4*i]*sumdv), fexp2(a[4*i+1]*sumdv),
                                fexp2(a[4*i+2]*sumdv), fexp2(a[4*i+3]*sumdv));
        ((float4*)(S + o))[i] = sv;
        ((float4*)(P + o))[i] = pv;
    }
}

// Pass 2: compose chunk states serially, float4-vectorized.
__global__ void scan_p2(const float4* __restrict__ P4, const float4* __restrict__ S4,
                        float4* __restrict__ X4) {
    int t = blockIdx.x * 256 + threadIdx.x;   // 0 .. DI*16/4-1
    const int stride = (DI * 16) / 4;
    float4 x = make_float4(0.f, 0.f, 0.f, 0.f);
    #pragma unroll 8
    for (int c = 0; c < NC; c++) {
        X4[(size_t)c * stride + t] = x;
        float4 pp = P4[(size_t)c * stride + t];
        float4 ss = S4[(size_t)c * stride + t];
        x.x = pp.x * x.x + ss.x;
        x.y = pp.y * x.y + ss.y;
        x.z = pp.z * x.z + ss.z;
        x.w = pp.w * x.w + ss.w;
    }
}

// Pass 3: re-run chunk from true initial state; always applies silu(res) gate.
__global__ __launch_bounds__(256) void scan_p3(const float* __restrict__ xr,
        const float* __restrict__ delta, const float* __restrict__ xdbl,
        const float* __restrict__ cw, const float* __restrict__ cb,
        const float* __restrict__ A_log, const float* __restrict__ Dp,
        const float* __restrict__ X,
        float* __restrict__ y, unsigned short* __restrict__ yb) {
    int c = blockIdx.x;
    int d = blockIdx.y * 256 + threadIdx.x;
    int l0 = c * LC;
    __shared__ float Bsh[LC][16], Csh[LC][16];
    __shared__ float cwsh[4][LC];
    __shared__ float cbsh[LC];
    {
        int t = threadIdx.x;
        #pragma unroll
        for (int i = t; i < LC * 16; i += 256) {
            int ll = i >> 4, q = i & 15;
            size_t row = (size_t)(l0 + ll) * 128;
            Bsh[ll][q] = xdbl[row + 64 + q];
            Csh[ll][q] = xdbl[row + 80 + q];
        }
        if (t < LC) {
            cbsh[t] = cb[l0 + t];
            #pragma unroll
            for (int k = 0; k < 4; k++) cwsh[k][t] = cw[k * SEQ + l0 + t];
        }
    }
    __syncthreads();
    float a[16];
    #pragma unroll
    for (int i = 0; i < 4; i++) {
        float4 al = ((const float4*)(A_log + (size_t)d * 16))[i];
        a[4*i+0] = -fexp(al.x) * LOG2E; a[4*i+1] = -fexp(al.y) * LOG2E;
        a[4*i+2] = -fexp(al.z) * LOG2E; a[4*i+3] = -fexp(al.w) * LOG2E;
    }
    float s[16];
    size_t o = ((size_t)c * DI + d) * 16;
    #pragma unroll
    for (int i = 0; i < 4; i++) {
        float4 xv4 = ((const float4*)(X + o))[i];
        s[4*i] = xv4.x; s[4*i+1] = xv4.y; s[4*i+2] = xv4.z; s[4*i+3] = xv4.w;
    }
    float Dv = Dp[d];
    for (int ll = 0; ll < LC; ll++) {
        size_t lrow = (size_t)(l0 + ll);
        float dv = delta[lrow * DI + d];
        const float* xrow = xr + lrow * 4096;
        float accv = cbsh[ll];
        #pragma unroll
        for (int k = 0; k < 4; k++) {
            int cc = d + k - 1;
            if (cc >= 0 && cc < DI) accv += xrow[cc] * cwsh[k][ll];
        }
        float xv = siluf(accv);
        float du = dv * xv;
        float yv = 0.f;
        #pragma unroll
        for (int n = 0; n < 16; n++) {
            s[n] = fexp2(dv * a[n]) * s[n] + du * Bsh[ll][n];
            yv += s[n] * Csh[ll][n];
        }
        float res = xrow[2048 + d];
        float val = (yv + xv * Dv) * siluf(res);
        if (yb) yb[lrow * DI + d] = f2bf(val);
        else    y[lrow * DI + d] = val;
    }
}

extern "C" void kernel_launch(void* const* d_in, const int* in_sizes, int n_in,
                              void* d_out, int out_size, void* d_ws, size_t ws_size,
                              hipStream_t stream) {
    const int*   ids        = (const int*)d_in[0];
    const float* embed      = (const float*)d_in[1];
    const float* norm_scale = (const float*)d_in[2];
    const float* in_w       = (const float*)d_in[3];
    const float* in_b       = (const float*)d_in[4];
    const float* conv_w     = (const float*)d_in[5];
    const float* conv_b     = (const float*)d_in[6];
    const float* x_proj_w   = (const float*)d_in[7];
    const float* dt_w       = (const float*)d_in[8];
    const float* dt_b       = (const float*)d_in[9];
    const float* out_w      = (const float*)d_in[10];
    const float* out_b      = (const float*)d_in[11];
    const float* A_log      = (const float*)d_in[12];
    const float* Dp         = (const float*)d_in[13];
    const float* norm_f     = (const float*)d_in[14];
    const float* lm_w       = (const float*)d_in[15];

    float* out = (float*)d_out;

    // ---- workspace layout ----
    char* p = (char*)d_ws;
    float* h  = (float*)p;  p += (size_t)SEQ * DM * 4;
    float* hn = (float*)p;  p += (size_t)SEQ * DM * 4;
    size_t base = (size_t)p - (size_t)d_ws;
    const size_t SZ_UB    = (size_t)SEQ * DM * 2;
    const size_t SZ_YB    = (size_t)SEQ * DI * 2;
    const size_t SZ_HNB   = (size_t)SEQ * DM * 2;
    const size_t SZ_INWT  = (size_t)2 * NINP * DM * 2;   // in_proj + xproj + delta rows (padded)
    const size_t SZ_OUTWT = (size_t)2 * DM * DI * 2;
    const size_t SZ_LMWT  = (size_t)NVOCP * DM * 2;      // padded to 32768 rows
    size_t need_mid  = base + SZ_UB + SZ_YB + SZ_HNB + SZ_INWT + SZ_OUTWT;
    size_t need_full = need_mid + SZ_LMWT;
    bool mid  = ws_size >= need_mid;
    bool full = ws_size >= need_full;

    unsigned short *u_b = nullptr, *y_b = nullptr, *hn_b = nullptr;
    unsigned short *in_wT = nullptr, *out_wT = nullptr, *lm_wT = nullptr;
    if (mid) {
        u_b    = (unsigned short*)p; p += SZ_UB;
        y_b    = (unsigned short*)p; p += SZ_YB;
        hn_b   = (unsigned short*)p; p += SZ_HNB;
        in_wT  = (unsigned short*)p; p += SZ_INWT;
        out_wT = (unsigned short*)p; p += SZ_OUTWT;
        if (full) { lm_wT = (unsigned short*)p; p += SZ_LMWT; }
    }

    // transient scratch inside d_out (fully rewritten by final GEMM)
    float* u     = out;                          // SEQ*DM (fallback only)
    float* xr    = u + (size_t)SEQ * DM;         // SEQ*4096
    float* xdbl  = xr + (size_t)SEQ * 4096;      // SEQ*128
    float* delta = xdbl + (size_t)SEQ * 128;     // SEQ*DI
    float* y     = delta + (size_t)SEQ * DI;     // SEQ*DI (fallback only)
    float* Pbuf  = y + (size_t)SEQ * DI;         // NC*DI*16
    float* Sbuf  = Pbuf + (size_t)NC * DI * 16;  // NC*DI*16
    float* Xbuf  = Sbuf + (size_t)NC * DI * 16;  // NC*DI*16

    // ---- weight convert+transpose + delta-weight composition ----
    if (mid) {
        int nblocks = full ? 11328 : 3136;
        transpose_all<<<nblocks, dim3(32, 8), 0, stream>>>(
            in_w, x_proj_w, out_w, lm_w, in_wT, out_wT, lm_wT);
        compose_dtw<<<dim3(DI / 64, DM / 64, 2), 256, 0, stream>>>(
            x_proj_w, dt_w, in_wT);
        (void)hipFuncSetAttribute((const void*)gemm_256<0>,
                                  hipFuncAttributeMaxDynamicSharedMemorySize, 98304);
        (void)hipFuncSetAttribute((const void*)gemm_256<1>,
                                  hipFuncAttributeMaxDynamicSharedMemorySize, 98304);
    }

    for (int L = 0; L < 2; L++) {
        // L0: fused embed-gather + rmsnorm (writes h and u_b/u)
        rmsnorm_kernel<<<SEQ, 256, 0, stream>>>(
            h, norm_scale + (size_t)L * DM, u, u_b,
            (L == 0) ? ids : nullptr, embed, h);
        if (mid) {
            // fused in_proj + xproj + dt_proj on the 256^2 pipelined structure
            gemm_256<1><<<dim3(SEQ / 256, NINP / 256), 1024, 98304, stream>>>(
                u_b, in_wT + (size_t)L * NINP * DM, xr, in_b + (size_t)L * 4096,
                xdbl, delta, dt_b + (size_t)L * DI, SEQ, NINP, DM);
        } else {
            gemm_f32<0><<<dim3(4096 / 64, SEQ / 64), dim3(16, 16), 0, stream>>>(
                u, DM, in_w + (size_t)L * DM * 4096, in_b + (size_t)L * 4096, nullptr, xr,
                SEQ, 4096, DM);
            xproj_kernel<<<SEQ / 4, 128, 0, stream>>>(u, x_proj_w + (size_t)L * DM * 96, xdbl);
            gemm_f32<1><<<dim3(DI / 64, SEQ / 64), dim3(16, 16), 0, stream>>>(
                xdbl, 128, dt_w + (size_t)L * DTR * DI, dt_b + (size_t)L * DI, nullptr, delta,
                SEQ, DI, DTR);
        }
        scan_p1<<<dim3(NC, DI / 256), 256, 0, stream>>>(
            xr, delta, xdbl, conv_w + (size_t)L * 4 * SEQ, conv_b + (size_t)L * SEQ,
            A_log + (size_t)L * DI * DST, Pbuf, Sbuf);
        scan_p2<<<(DI * 16 / 4) / 256, 256, 0, stream>>>(
            (const float4*)Pbuf, (const float4*)Sbuf, (float4*)Xbuf);
        scan_p3<<<dim3(NC, DI / 256), 256, 0, stream>>>(
            xr, delta, xdbl, conv_w + (size_t)L * 4 * SEQ, conv_b + (size_t)L * SEQ,
            A_log + (size_t)L * DI * DST, Dp + (size_t)L * DI, Xbuf, y, y_b);
        if (mid) {
            gemm_bf16<1, 1, 0><<<dim3(SEQ / 128, DM / 128), 256, 0, stream>>>(
                y_b, DI, out_wT + (size_t)L * DM * DI, out_b + (size_t)L * DM, h, h,
                SEQ, DM, DI);
        } else {
            gemm_f32<0><<<dim3(DM / 64, SEQ / 64), dim3(16, 16), 0, stream>>>(
                y, DI, out_w + (size_t)L * DI * DM, out_b + (size_t)L * DM, h, h,
                SEQ, DM, DI);
        }
    }

    rmsnorm_kernel<<<SEQ, 256, 0, stream>>>(h, norm_f, hn, full ? hn_b : nullptr,
                                            nullptr, nullptr, nullptr);
    if (full) {
        gemm_256<0><<<dim3(SEQ / 256, NVOCP / 256), 1024, 98304, stream>>>(
            hn_b, lm_wT, out, nullptr, nullptr, nullptr, nullptr, SEQ, NVOC, DM);
    } else {
        gemm_f32<0><<<dim3(NVOC / 64, SEQ / 64), dim3(16, 16), 0, stream>>>(
            hn, DM, lm_w, nullptr, nullptr, out, SEQ, NVOC, DM);
    }
}

// Round 24
// 655.470 us; speedup vs baseline: 1.0107x; 1.0107x over previous
//
#include <hip/hip_runtime.h>
#include <hip/hip_bf16.h>

#define SEQ 2048
#define DM  1024
#define DI  2048
#define DST 16
#define DTR 64
#define NVOC 32000
#define NVOCP 32768   // padded N for lm_head 256-tile grid
#define NIN  6272     // logical fused in_proj N: 4096 (x,res) + 128 (xdbl) + 2048 (delta)
#define NINP 6400     // padded to 25 tiles of 256
#define NC  64    // scan chunks
#define LC  32    // chunk length; NC*LC == SEQ

typedef __bf16 bf16x8 __attribute__((ext_vector_type(8)));
typedef float  f32x4  __attribute__((ext_vector_type(4)));

__device__ __forceinline__ float fexp(float x) { return __expf(x); }   // v_exp path
__device__ __forceinline__ float siluf(float x) { return x / (1.f + fexp(-x)); }
__device__ __forceinline__ float softplusf(float x) {
    return fmaxf(x, 0.f) + log1pf(fexp(-fabsf(x)));
}
__device__ __forceinline__ unsigned short f2bf(float f) {
    union { __hip_bfloat16 h; unsigned short u; } c;
    c.h = __float2bfloat16(f);
    return c.u;
}

// rmsnorm with optional embed-gather input (ids!=null: x := embed[ids[l]], also writes h).
__global__ void rmsnorm_kernel(const float* __restrict__ x, const float* __restrict__ w,
                               float* __restrict__ o, unsigned short* __restrict__ ob,
                               const int* __restrict__ ids, const float* __restrict__ embed,
                               float* __restrict__ hout) {
    int l = blockIdx.x;
    int t = threadIdx.x; // 256
    float4 v;
    if (ids) {
        int row = ids[l];
        v = ((const float4*)(embed + (size_t)row * DM))[t];
        ((float4*)(hout + (size_t)l * DM))[t] = v;   // h = gathered row (residual base)
    } else {
        v = ((const float4*)(x + (size_t)l * DM))[t];
    }
    float ss = v.x*v.x + v.y*v.y + v.z*v.z + v.w*v.w;
    #pragma unroll
    for (int m = 32; m; m >>= 1) ss += __shfl_xor(ss, m);
    __shared__ float red[4];
    if ((t & 63) == 0) red[t >> 6] = ss;
    __syncthreads();
    float tot = red[0] + red[1] + red[2] + red[3];
    float sc = rsqrtf(tot * (1.f / DM) + 1e-6f);
    float4 wv = ((const float4*)w)[t];
    float4 ov;
    ov.x = v.x * sc * wv.x;
    ov.y = v.y * sc * wv.y;
    ov.z = v.z * sc * wv.z;
    ov.w = v.w * sc * wv.w;
    if (ob) {
        uint2 pk;
        pk.x = (unsigned)f2bf(ov.x) | ((unsigned)f2bf(ov.y) << 16);
        pk.y = (unsigned)f2bf(ov.z) | ((unsigned)f2bf(ov.w) << 16);
        ((uint2*)(ob + (size_t)l * DM))[t] = pk;
    } else {
        ((float4*)(o + (size_t)l * DM))[t] = ov;
    }
}

// ===== single fused transpose, 64x64 tiles: f32 [K][N] -> bf16 [Npad][K] =====
__global__ void transpose_all(const float* __restrict__ in_w, const float* __restrict__ xp_w,
                              const float* __restrict__ out_w,
                              const float* __restrict__ lm_w,
                              unsigned short* __restrict__ in_wT, unsigned short* __restrict__ out_wT,
                              unsigned short* __restrict__ lm_wT) {
    int b = blockIdx.x;
    const float* W; unsigned short* WT; int K, N, Np, loc;
    if      (b < 1024)  { W = in_w;                        WT = in_wT;                                              K=1024; N=4096;  Np=4096;  loc = b; }
    else if (b < 1056)  { W = xp_w;                        WT = in_wT + (size_t)4096 * 1024;                        K=1024; N=96;    Np=128;   loc = b - 1024; }
    else if (b < 2080)  { W = in_w + (size_t)1024 * 4096;  WT = in_wT + (size_t)NINP * 1024;                        K=1024; N=4096;  Np=4096;  loc = b - 1056; }
    else if (b < 2112)  { W = xp_w + (size_t)1024 * 96;    WT = in_wT + (size_t)NINP * 1024 + (size_t)4096 * 1024;  K=1024; N=96;    Np=128;   loc = b - 2080; }
    else if (b < 2624)  { W = out_w;                       WT = out_wT;                                             K=2048; N=1024;  Np=1024;  loc = b - 2112; }
    else if (b < 3136)  { W = out_w + (size_t)2048 * 1024; WT = out_wT + (size_t)1024 * 2048;                       K=2048; N=1024;  Np=1024;  loc = b - 2624; }
    else                { if (!lm_wT) return; W = lm_w;    WT = lm_wT;                                              K=1024; N=32000; Np=32768; loc = b - 3136; }
    int tiles_x = Np >> 6;
    int n0 = (loc % tiles_x) * 64, k0 = (loc / tiles_x) * 64;
    __shared__ float tile[64][65];   // [n][k]
    int t = threadIdx.y * 32 + threadIdx.x;   // 0..255
    {
        int kk = t >> 4;            // 0..15
        int n4 = (t & 15) * 4;      // 0..60
        #pragma unroll
        for (int i = 0; i < 4; i++) {
            int k = kk + i * 16;
            int n = n0 + n4;
            float4 v;
            if (n < N) v = *(const float4*)&W[(size_t)(k0 + k) * N + n];
            else       v = make_float4(0.f, 0.f, 0.f, 0.f);
            tile[n4 + 0][k] = v.x;
            tile[n4 + 1][k] = v.y;
            tile[n4 + 2][k] = v.z;
            tile[n4 + 3][k] = v.w;
        }
    }
    __syncthreads();
    {
        int nr = t >> 3;            // 0..31
        int u  = t & 7;             // k-group: 8 bf16 each
        #pragma unroll
        for (int pass = 0; pass < 2; pass++) {
            int nn = pass * 32 + nr;
            unsigned short tmp[8];
            #pragma unroll
            for (int j = 0; j < 8; j++) tmp[j] = f2bf(tile[nn][u * 8 + j]);
            uint4 pk;
            pk.x = (unsigned)tmp[0] | ((unsigned)tmp[1] << 16);
            pk.y = (unsigned)tmp[2] | ((unsigned)tmp[3] << 16);
            pk.z = (unsigned)tmp[4] | ((unsigned)tmp[5] << 16);
            pk.w = (unsigned)tmp[6] | ((unsigned)tmp[7] << 16);
            *(uint4*)&WT[(size_t)(n0 + nn) * K + k0 + u * 8] = pk;
        }
    }
}

// ===== compose W_effT = (xp_w[:, :64] @ dt_w)^T, bf16 [2048][1024], fp32 math =====
__global__ __launch_bounds__(256) void compose_dtw(const float* __restrict__ xp_w,
                                                   const float* __restrict__ dt_w,
                                                   unsigned short* __restrict__ in_wT) {
    int n0 = blockIdx.x * 64, k0 = blockIdx.y * 64, L = blockIdx.z;
    const float* xp = xp_w + (size_t)L * DM * 96;
    const float* dw = dt_w + (size_t)L * DTR * DI;
    unsigned short* WT = in_wT + (size_t)L * NINP * 1024 + (size_t)4224 * 1024;
    __shared__ float xps[64][65];   // [k][r]
    __shared__ float dts[64][65];   // [r][n]
    int t = threadIdx.x;
    for (int i = t; i < 64 * 64; i += 256) {
        int row = i >> 6, col = i & 63;
        xps[row][col] = xp[(size_t)(k0 + row) * 96 + col];       // r = col < 64
        dts[row][col] = dw[(size_t)row * DI + n0 + col];
    }
    __syncthreads();
    int n = t & 63, kg = t >> 6;    // 4 k-groups of 16
    float acc[16] = {};
    for (int r = 0; r < 64; r++) {
        float d = dts[r][n];
        #pragma unroll
        for (int k = 0; k < 16; k++)
            acc[k] += xps[kg * 16 + k][r] * d;
    }
    #pragma unroll
    for (int k = 0; k < 16; k++)
        WT[(size_t)(n0 + n) * 1024 + k0 + kg * 16 + k] = f2bf(acc[k]);
}

// Generic fp32 GEMM (fallback only)
template<int ACT>
__global__ __launch_bounds__(256) void gemm_f32(const float* __restrict__ A, int lda,
                                                const float* __restrict__ B,
                                                const float* __restrict__ bias,
                                                const float* __restrict__ add,
                                                float* __restrict__ C,
                                                int M, int N, int K) {
    __shared__ float As[16][68];
    __shared__ float Bs[16][64];
    int tx = threadIdx.x, ty = threadIdx.y;
    int t = ty * 16 + tx;
    int m0 = blockIdx.y * 64, n0 = blockIdx.x * 64;
    float acc[4][4] = {};
    for (int k0 = 0; k0 < K; k0 += 16) {
        #pragma unroll
        for (int i = 0; i < 4; i++) {
            int idx = t + i * 256;
            int mm = idx >> 4, kk = idx & 15;
            As[kk][mm] = A[(size_t)(m0 + mm) * lda + k0 + kk];
            int nn = idx & 63, k2 = idx >> 6;
            Bs[k2][nn] = B[(size_t)(k0 + k2) * N + n0 + nn];
        }
        __syncthreads();
        #pragma unroll
        for (int kk = 0; kk < 16; kk++) {
            float4 a = *(const float4*)&As[kk][ty * 4];
            float4 b = *(const float4*)&Bs[kk][tx * 4];
            acc[0][0] += a.x*b.x; acc[0][1] += a.x*b.y; acc[0][2] += a.x*b.z; acc[0][3] += a.x*b.w;
            acc[1][0] += a.y*b.x; acc[1][1] += a.y*b.y; acc[1][2] += a.y*b.z; acc[1][3] += a.y*b.w;
            acc[2][0] += a.z*b.x; acc[2][1] += a.z*b.y; acc[2][2] += a.z*b.z; acc[2][3] += a.z*b.w;
            acc[3][0] += a.w*b.x; acc[3][1] += a.w*b.y; acc[3][2] += a.w*b.z; acc[3][3] += a.w*b.w;
        }
        __syncthreads();
    }
    #pragma unroll
    for (int i = 0; i < 4; i++) {
        int row = m0 + ty * 4 + i;
        float4 r;
        float* pr = &r.x;
        #pragma unroll
        for (int j = 0; j < 4; j++) {
            int col = n0 + tx * 4 + j;
            float v = acc[i][j];
            if (bias) v += bias[col];
            if (add)  v += add[(size_t)row * N + col];
            if (ACT == 1) v = softplusf(v);
            pr[j] = v;
        }
        *(float4*)&C[(size_t)row * N + n0 + tx * 4] = r;
    }
}

// bf16 MFMA GEMM (m97 structure): 128x128 tile, BK=32. Used for out_proj.
template<int BIAS, int ADD, int ACT>
__global__ __launch_bounds__(256) void gemm_bf16(const unsigned short* __restrict__ A, int lda,
                                                 const unsigned short* __restrict__ BT,
                                                 const float* __restrict__ bias,
                                                 const float* __restrict__ add,
                                                 float* __restrict__ C,
                                                 int M, int N, int K) {
    __shared__ unsigned short As[128 * 32];
    __shared__ unsigned short Bs[128 * 32];
    int t = threadIdx.x;
    int w = t >> 6, l = t & 63;
    int wm = w >> 1, wn = w & 1;
    int m0 = blockIdx.x * 128;
    int n0 = blockIdx.y * 128;
    int lr = l & 15, lk = (l >> 4) * 8;
    int sr = t >> 2, sc = (t & 3) * 8;     // staging: row, k-offset
    f32x4 acc[4][4] = {};
    for (int k0 = 0; k0 < K; k0 += 32) {
        const unsigned short* ga = A  + (size_t)(m0 + sr) * lda + k0 + sc;
        const unsigned short* gb = BT + (size_t)(n0 + sr) * K + k0 + sc;
        unsigned short* la = As + w * 512;   // wave-uniform base; HW adds lane*16B
        unsigned short* lb = Bs + w * 512;
        __builtin_amdgcn_global_load_lds((const __attribute__((address_space(1))) void*)ga,
            (__attribute__((address_space(3))) void*)la, 16, 0, 0);
        __builtin_amdgcn_global_load_lds((const __attribute__((address_space(1))) void*)(ga + (size_t)64 * lda),
            (__attribute__((address_space(3))) void*)(la + 2048), 16, 0, 0);
        __builtin_amdgcn_global_load_lds((const __attribute__((address_space(1))) void*)gb,
            (__attribute__((address_space(3))) void*)(lb), 16, 0, 0);
        __builtin_amdgcn_global_load_lds((const __attribute__((address_space(1))) void*)(gb + (size_t)64 * K),
            (__attribute__((address_space(3))) void*)(lb + 2048), 16, 0, 0);
        __syncthreads();
        bf16x8 af[4], bfr[4];
        #pragma unroll
        for (int i = 0; i < 4; i++) {
            af[i]  = *reinterpret_cast<const bf16x8*>(&As[(wm * 64 + i * 16 + lr) * 32 + lk]);
            bfr[i] = *reinterpret_cast<const bf16x8*>(&Bs[(wn * 64 + i * 16 + lr) * 32 + lk]);
        }
        #pragma unroll
        for (int i = 0; i < 4; i++)
            #pragma unroll
            for (int j = 0; j < 4; j++)
                acc[i][j] = __builtin_amdgcn_mfma_f32_16x16x32_bf16(af[i], bfr[j], acc[i][j], 0, 0, 0);
        __syncthreads();
    }
    int cr = (l >> 4) * 4;
    #pragma unroll
    for (int i = 0; i < 4; i++) {
        #pragma unroll
        for (int j = 0; j < 4; j++) {
            int col = n0 + wn * 64 + j * 16 + lr;
            float bv = BIAS ? bias[col] : 0.f;
            #pragma unroll
            for (int rr = 0; rr < 4; rr++) {
                int row = m0 + wm * 64 + i * 16 + cr + rr;
                float v = acc[i][j][rr] + bv;
                if (ADD) v += add[(size_t)row * N + col];
                if (ACT == 1) v = softplusf(v);
                C[(size_t)row * N + col] = v;
            }
        }
    }
}

// ==== 256x256 3-buf counted-vmcnt GEMM body ====
template<int EPI>
__global__ __launch_bounds__(1024, 4) void gemm_256(
        const unsigned short* __restrict__ A,
        const unsigned short* __restrict__ BT,
        float* __restrict__ C, const float* __restrict__ bias,
        float* __restrict__ xp_out, float* __restrict__ dout,
        const float* __restrict__ dt_bias,
        int M, int N, int K) {
    extern __shared__ unsigned short lds[];   // 3 x 16384 shorts (A|B per buf)
    const int t = threadIdx.x;
    const int w = t >> 6, l = t & 63;
    const int wr = w >> 2, wc = w & 3;        // 4x4 waves, 64x64 tile each
    int bxx = blockIdx.x, byy = blockIdx.y;
    if (gridDim.x == 8 && (gridDim.y & 7) == 0) {
        int lin = blockIdx.y * 8 + blockIdx.x;
        int xcd = lin & 7, i = lin >> 3;
        bxx = i & 7;
        byy = xcd * (gridDim.y >> 3) + (i >> 3);
    }
    const int m0 = bxx * 256, n0 = byy * 256;
    const int lr = l & 15;
    const int rowA = wr * 64 + lr;
    const int rowB = wc * 64 + lr;
    const int colR = (((l >> 4) ^ (lr & 3)) * 8);   // swizzled ds_read col (shorts)
    const int srow = t >> 2;                        // staging row 0..255
    const int scol = (((t & 3) ^ (srow & 3)) * 8);  // pre-swizzled global col
    const int NT = K >> 5;                          // BK=32
    f32x4 acc[4][4] = {};
    bf16x8 af[4], bf[4];

    const unsigned short* gA = A  + (size_t)(m0 + srow) * K + scol;
    const unsigned short* gB = BT + (size_t)(n0 + srow) * K + scol;

    #pragma unroll
    for (int pp = 0; pp < 2; pp++) {
        if (pp < NT) {
            unsigned short* Ld = lds + pp * 16384;
            __builtin_amdgcn_global_load_lds(
                (const __attribute__((address_space(1))) void*)(gA + pp * 32),
                (__attribute__((address_space(3))) void*)(Ld + w * 512), 16, 0, 0);
            __builtin_amdgcn_global_load_lds(
                (const __attribute__((address_space(1))) void*)(gB + pp * 32),
                (__attribute__((address_space(3))) void*)(Ld + 8192 + w * 512), 16, 0, 0);
        }
    }

    for (int kt = 0; kt < NT; kt++) {
        if (kt >= NT - 2) { asm volatile("s_waitcnt vmcnt(0)" ::: "memory"); }
        else              { asm volatile("s_waitcnt vmcnt(2)" ::: "memory"); }
        __builtin_amdgcn_sched_barrier(0);
        __builtin_amdgcn_s_barrier();
        __builtin_amdgcn_sched_barrier(0);
        const unsigned short* Ab = lds + (kt % 3) * 16384;
        const unsigned short* Bb = Ab + 8192;
        #pragma unroll
        for (int i = 0; i < 4; i++)
            af[i] = *reinterpret_cast<const bf16x8*>(&Ab[(rowA + i * 16) * 32 + colR]);
        #pragma unroll
        for (int j = 0; j < 4; j++)
            bf[j] = *reinterpret_cast<const bf16x8*>(&Bb[(rowB + j * 16) * 32 + colR]);
        if (kt + 2 < NT) {
            unsigned short* Ld = lds + ((kt + 2) % 3) * 16384;
            __builtin_amdgcn_global_load_lds(
                (const __attribute__((address_space(1))) void*)(gA + (kt + 2) * 32),
                (__attribute__((address_space(3))) void*)(Ld + w * 512), 16, 0, 0);
            __builtin_amdgcn_global_load_lds(
                (const __attribute__((address_space(1))) void*)(gB + (kt + 2) * 32),
                (__attribute__((address_space(3))) void*)(Ld + 8192 + w * 512), 16, 0, 0);
        }
        __builtin_amdgcn_s_setprio(1);
        #pragma unroll
        for (int i = 0; i < 4; i++)
            #pragma unroll
            for (int j = 0; j < 4; j++)
                acc[i][j] = __builtin_amdgcn_mfma_f32_16x16x32_bf16(af[i], bf[j], acc[i][j], 0, 0, 0);
        __builtin_amdgcn_s_setprio(0);
    }

    // ---- epilogue: LDS transpose -> f32x4 coalesced stores ----
    float* cf = (float*)lds;   // [64][260] f32 = 66.6 KB (fits 96 KB dyn-LDS)
    const int cr = (l >> 4) * 4;
    for (int r = 0; r < 4; r++) {
        __syncthreads();   // previous round's reads complete before overwrite
        if (wr == r) {
            #pragma unroll
            for (int i = 0; i < 4; i++)
                #pragma unroll
                for (int j = 0; j < 4; j++) {
                    int col = wc * 64 + j * 16 + lr;
                    #pragma unroll
                    for (int rr = 0; rr < 4; rr++)
                        cf[(i * 16 + cr + rr) * 260 + col] = acc[i][j][rr];
                }
        }
        __syncthreads();
        #pragma unroll
        for (int pass = 0; pass < 4; pass++) {
            int row = pass * 16 + (t >> 6);
            int f4 = t & 63;
            f32x4 v = *(const f32x4*)&cf[row * 260 + f4 * 4];
            int grow = m0 + r * 64 + row;
            int gcol = n0 + f4 * 4;
            if (EPI == 0) {
                if (gcol < N)
                    __builtin_nontemporal_store(v, (f32x4*)&C[(size_t)grow * N + gcol]);
            } else {
                if (gcol < 4096) {
                    const f32x4 bv = *(const f32x4*)&bias[gcol];
                    v += bv;
                    *(f32x4*)&C[(size_t)grow * 4096 + gcol] = v;
                } else if (gcol < 4224) {
                    *(f32x4*)&xp_out[(size_t)grow * 128 + (gcol - 4096)] = v;
                } else if (gcol < NIN) {
                    int c2 = gcol - 4224;
                    const f32x4 bv = *(const f32x4*)&dt_bias[c2];
                    f32x4 o;
                    o[0] = softplusf(v[0] + bv[0]);
                    o[1] = softplusf(v[1] + bv[1]);
                    o[2] = softplusf(v[2] + bv[2]);
                    o[3] = softplusf(v[3] + bv[3]);
                    *(f32x4*)&dout[(size_t)grow * DI + c2] = o;
                }
            }
        }
    }
}

// fallback xproj (fp32, stride-128 output)
__global__ void xproj_kernel(const float* __restrict__ u, const float* __restrict__ xw,
                             float* __restrict__ xdbl) {
    int l0 = blockIdx.x * 4;
    int t = threadIdx.x; // 128
    __shared__ float us[4][DM];
    for (int i = t; i < 4 * DM; i += 128) us[i >> 10][i & 1023] = u[(size_t)l0 * DM + i];
    __syncthreads();
    if (t < 96) {
        float a0 = 0.f, a1 = 0.f, a2 = 0.f, a3 = 0.f;
        for (int k = 0; k < DM; k++) {
            float wv = xw[(size_t)k * 96 + t];
            a0 += us[0][k] * wv; a1 += us[1][k] * wv;
            a2 += us[2][k] * wv; a3 += us[3][k] * wv;
        }
        xdbl[(size_t)(l0 + 0) * 128 + t] = a0;
        xdbl[(size_t)(l0 + 1) * 128 + t] = a1;
        xdbl[(size_t)(l0 + 2) * 128 + t] = a2;
        xdbl[(size_t)(l0 + 3) * 128 + t] = a3;
    }
}

// ---- chunked selective scan with fused conv+silu (x = silu(conv(xr))) ----
__global__ __launch_bounds__(256) void scan_p1(const float* __restrict__ xr,
        const float* __restrict__ delta, const float* __restrict__ xdbl,
        const float* __restrict__ cw, const float* __restrict__ cb,
        const float* __restrict__ A_log, float* __restrict__ P, float* __restrict__ S) {
    int c = blockIdx.x;
    int d = blockIdx.y * 256 + threadIdx.x;
    int l0 = c * LC;
    __shared__ float Bsh[LC][16];
    __shared__ float cwsh[4][LC];
    __shared__ float cbsh[LC];
    {
        int t = threadIdx.x;
        #pragma unroll
        for (int i = t; i < LC * 16; i += 256) {
            int ll = i >> 4, q = i & 15;
            Bsh[ll][q] = xdbl[(size_t)(l0 + ll) * 128 + 64 + q];
        }
        if (t < LC) {
            cbsh[t] = cb[l0 + t];
            #pragma unroll
            for (int k = 0; k < 4; k++) cwsh[k][t] = cw[k * SEQ + l0 + t];
        }
    }
    __syncthreads();
    float a[16];
    #pragma unroll
    for (int i = 0; i < 4; i++) {
        float4 al = ((const float4*)(A_log + (size_t)d * 16))[i];
        a[4*i+0] = -fexp(al.x); a[4*i+1] = -fexp(al.y);
        a[4*i+2] = -fexp(al.z); a[4*i+3] = -fexp(al.w);
    }
    float s[16] = {};
    float sumdv = 0.f;
    for (int ll = 0; ll < LC; ll++) {
        size_t lrow = (size_t)(l0 + ll);
        float dv = delta[lrow * DI + d];
        const float* xrow = xr + lrow * 4096;
        float accv = cbsh[ll];
        #pragma unroll
        for (int k = 0; k < 4; k++) {
            int cc = d + k - 1;
            if (cc >= 0 && cc < DI) accv += xrow[cc] * cwsh[k][ll];
        }
        float xv = siluf(accv);
        float du = dv * xv;
        sumdv += dv;
        #pragma unroll
        for (int n = 0; n < 16; n++)
            s[n] = fexp(dv * a[n]) * s[n] + du * Bsh[ll][n];
    }
    size_t o = ((size_t)c * DI + d) * 16;
    #pragma unroll
    for (int i = 0; i < 4; i++) {
        float4 sv = make_float4(s[4*i], s[4*i+1], s[4*i+2], s[4*i+3]);
        float4 pv = make_float4(fexp(a[4*i]*sumdv), fexp(a[4*i+1]*sumdv),
                                fexp(a[4*i+2]*sumdv), fexp(a[4*i+3]*sumdv));
        ((float4*)(S + o))[i] = sv;
        ((float4*)(P + o))[i] = pv;
    }
}

// Pass 2: compose chunk states serially, float4-vectorized.
__global__ void scan_p2(const float4* __restrict__ P4, const float4* __restrict__ S4,
                        float4* __restrict__ X4) {
    int t = blockIdx.x * 256 + threadIdx.x;   // 0 .. DI*16/4-1
    const int stride = (DI * 16) / 4;
    float4 x = make_float4(0.f, 0.f, 0.f, 0.f);
    #pragma unroll 8
    for (int c = 0; c < NC; c++) {
        X4[(size_t)c * stride + t] = x;
        float4 pp = P4[(size_t)c * stride + t];
        float4 ss = S4[(size_t)c * stride + t];
        x.x = pp.x * x.x + ss.x;
        x.y = pp.y * x.y + ss.y;
        x.z = pp.z * x.z + ss.z;
        x.w = pp.w * x.w + ss.w;
    }
}

// Pass 3: re-run chunk from true initial state; always applies silu(res) gate.
__global__ __launch_bounds__(256) void scan_p3(const float* __restrict__ xr,
        const float* __restrict__ delta, const float* __restrict__ xdbl,
        const float* __restrict__ cw, const float* __restrict__ cb,
        const float* __restrict__ A_log, const float* __restrict__ Dp,
        const float* __restrict__ X,
        float* __restrict__ y, unsigned short* __restrict__ yb) {
    int c = blockIdx.x;
    int d = blockIdx.y * 256 + threadIdx.x;
    int l0 = c * LC;
    __shared__ float Bsh[LC][16], Csh[LC][16];
    __shared__ float cwsh[4][LC];
    __shared__ float cbsh[LC];
    {
        int t = threadIdx.x;
        #pragma unroll
        for (int i = t; i < LC * 16; i += 256) {
            int ll = i >> 4, q = i & 15;
            size_t row = (size_t)(l0 + ll) * 128;
            Bsh[ll][q] = xdbl[row + 64 + q];
            Csh[ll][q] = xdbl[row + 80 + q];
        }
        if (t < LC) {
            cbsh[t] = cb[l0 + t];
            #pragma unroll
            for (int k = 0; k < 4; k++) cwsh[k][t] = cw[k * SEQ + l0 + t];
        }
    }
    __syncthreads();
    float a[16];
    #pragma unroll
    for (int i = 0; i < 4; i++) {
        float4 al = ((const float4*)(A_log + (size_t)d * 16))[i];
        a[4*i+0] = -fexp(al.x); a[4*i+1] = -fexp(al.y);
        a[4*i+2] = -fexp(al.z); a[4*i+3] = -fexp(al.w);
    }
    float s[16];
    size_t o = ((size_t)c * DI + d) * 16;
    #pragma unroll
    for (int i = 0; i < 4; i++) {
        float4 xv4 = ((const float4*)(X + o))[i];
        s[4*i] = xv4.x; s[4*i+1] = xv4.y; s[4*i+2] = xv4.z; s[4*i+3] = xv4.w;
    }
    float Dv = Dp[d];
    for (int ll = 0; ll < LC; ll++) {
        size_t lrow = (size_t)(l0 + ll);
        float dv = delta[lrow * DI + d];
        const float* xrow = xr + lrow * 4096;
        float accv = cbsh[ll];
        #pragma unroll
        for (int k = 0; k < 4; k++) {
            int cc = d + k - 1;
            if (cc >= 0 && cc < DI) accv += xrow[cc] * cwsh[k][ll];
        }
        float xv = siluf(accv);
        float du = dv * xv;
        float yv = 0.f;
        #pragma unroll
        for (int n = 0; n < 16; n++) {
            s[n] = fexp(dv * a[n]) * s[n] + du * Bsh[ll][n];
            yv += s[n] * Csh[ll][n];
        }
        float res = xrow[2048 + d];
        float val = (yv + xv * Dv) * siluf(res);
        if (yb) yb[lrow * DI + d] = f2bf(val);
        else    y[lrow * DI + d] = val;
    }
}

extern "C" void kernel_launch(void* const* d_in, const int* in_sizes, int n_in,
                              void* d_out, int out_size, void* d_ws, size_t ws_size,
                              hipStream_t stream) {
    const int*   ids        = (const int*)d_in[0];
    const float* embed      = (const float*)d_in[1];
    const float* norm_scale = (const float*)d_in[2];
    const float* in_w       = (const float*)d_in[3];
    const float* in_b       = (const float*)d_in[4];
    const float* conv_w     = (const float*)d_in[5];
    const float* conv_b     = (const float*)d_in[6];
    const float* x_proj_w   = (const float*)d_in[7];
    const float* dt_w       = (const float*)d_in[8];
    const float* dt_b       = (const float*)d_in[9];
    const float* out_w      = (const float*)d_in[10];
    const float* out_b      = (const float*)d_in[11];
    const float* A_log      = (const float*)d_in[12];
    const float* Dp         = (const float*)d_in[13];
    const float* norm_f     = (const float*)d_in[14];
    const float* lm_w       = (const float*)d_in[15];

    float* out = (float*)d_out;

    // ---- workspace layout ----
    char* p = (char*)d_ws;
    float* h  = (float*)p;  p += (size_t)SEQ * DM * 4;
    float* hn = (float*)p;  p += (size_t)SEQ * DM * 4;
    size_t base = (size_t)p - (size_t)d_ws;
    const size_t SZ_UB    = (size_t)SEQ * DM * 2;
    const size_t SZ_YB    = (size_t)SEQ * DI * 2;
    const size_t SZ_HNB   = (size_t)SEQ * DM * 2;
    const size_t SZ_INWT  = (size_t)2 * NINP * DM * 2;   // in_proj + xproj + delta rows (padded)
    const size_t SZ_OUTWT = (size_t)2 * DM * DI * 2;
    const size_t SZ_LMWT  = (size_t)NVOCP * DM * 2;      // padded to 32768 rows
    size_t need_mid  = base + SZ_UB + SZ_YB + SZ_HNB + SZ_INWT + SZ_OUTWT;
    size_t need_full = need_mid + SZ_LMWT;
    bool mid  = ws_size >= need_mid;
    bool full = ws_size >= need_full;

    unsigned short *u_b = nullptr, *y_b = nullptr, *hn_b = nullptr;
    unsigned short *in_wT = nullptr, *out_wT = nullptr, *lm_wT = nullptr;
    if (mid) {
        u_b    = (unsigned short*)p; p += SZ_UB;
        y_b    = (unsigned short*)p; p += SZ_YB;
        hn_b   = (unsigned short*)p; p += SZ_HNB;
        in_wT  = (unsigned short*)p; p += SZ_INWT;
        out_wT = (unsigned short*)p; p += SZ_OUTWT;
        if (full) { lm_wT = (unsigned short*)p; p += SZ_LMWT; }
    }

    // transient scratch inside d_out (fully rewritten by final GEMM)
    float* u     = out;                          // SEQ*DM (fallback only)
    float* xr    = u + (size_t)SEQ * DM;         // SEQ*4096
    float* xdbl  = xr + (size_t)SEQ * 4096;      // SEQ*128
    float* delta = xdbl + (size_t)SEQ * 128;     // SEQ*DI
    float* y     = delta + (size_t)SEQ * DI;     // SEQ*DI (fallback only)
    float* Pbuf  = y + (size_t)SEQ * DI;         // NC*DI*16
    float* Sbuf  = Pbuf + (size_t)NC * DI * 16;  // NC*DI*16
    float* Xbuf  = Sbuf + (size_t)NC * DI * 16;  // NC*DI*16

    // ---- weight convert+transpose + delta-weight composition ----
    if (mid) {
        int nblocks = full ? 11328 : 3136;
        transpose_all<<<nblocks, dim3(32, 8), 0, stream>>>(
            in_w, x_proj_w, out_w, lm_w, in_wT, out_wT, lm_wT);
        compose_dtw<<<dim3(DI / 64, DM / 64, 2), 256, 0, stream>>>(
            x_proj_w, dt_w, in_wT);
        (void)hipFuncSetAttribute((const void*)gemm_256<0>,
                                  hipFuncAttributeMaxDynamicSharedMemorySize, 98304);
        (void)hipFuncSetAttribute((const void*)gemm_256<1>,
                                  hipFuncAttributeMaxDynamicSharedMemorySize, 98304);
    }

    for (int L = 0; L < 2; L++) {
        // L0: fused embed-gather + rmsnorm (writes h and u_b/u)
        rmsnorm_kernel<<<SEQ, 256, 0, stream>>>(
            h, norm_scale + (size_t)L * DM, u, u_b,
            (L == 0) ? ids : nullptr, embed, h);
        if (mid) {
            // fused in_proj + xproj + dt_proj on the 256^2 pipelined structure
            gemm_256<1><<<dim3(SEQ / 256, NINP / 256), 1024, 98304, stream>>>(
                u_b, in_wT + (size_t)L * NINP * DM, xr, in_b + (size_t)L * 4096,
                xdbl, delta, dt_b + (size_t)L * DI, SEQ, NINP, DM);
        } else {
            gemm_f32<0><<<dim3(4096 / 64, SEQ / 64), dim3(16, 16), 0, stream>>>(
                u, DM, in_w + (size_t)L * DM * 4096, in_b + (size_t)L * 4096, nullptr, xr,
                SEQ, 4096, DM);
            xproj_kernel<<<SEQ / 4, 128, 0, stream>>>(u, x_proj_w + (size_t)L * DM * 96, xdbl);
            gemm_f32<1><<<dim3(DI / 64, SEQ / 64), dim3(16, 16), 0, stream>>>(
                xdbl, 128, dt_w + (size_t)L * DTR * DI, dt_b + (size_t)L * DI, nullptr, delta,
                SEQ, DI, DTR);
        }
        scan_p1<<<dim3(NC, DI / 256), 256, 0, stream>>>(
            xr, delta, xdbl, conv_w + (size_t)L * 4 * SEQ, conv_b + (size_t)L * SEQ,
            A_log + (size_t)L * DI * DST, Pbuf, Sbuf);
        scan_p2<<<(DI * 16 / 4) / 256, 256, 0, stream>>>(
            (const float4*)Pbuf, (const float4*)Sbuf, (float4*)Xbuf);
        scan_p3<<<dim3(NC, DI / 256), 256, 0, stream>>>(
            xr, delta, xdbl, conv_w + (size_t)L * 4 * SEQ, conv_b + (size_t)L * SEQ,
            A_log + (size_t)L * DI * DST, Dp + (size_t)L * DI, Xbuf, y, y_b);
        if (mid) {
            gemm_bf16<1, 1, 0><<<dim3(SEQ / 128, DM / 128), 256, 0, stream>>>(
                y_b, DI, out_wT + (size_t)L * DM * DI, out_b + (size_t)L * DM, h, h,
                SEQ, DM, DI);
        } else {
            gemm_f32<0><<<dim3(DM / 64, SEQ / 64), dim3(16, 16), 0, stream>>>(
                y, DI, out_w + (size_t)L * DI * DM, out_b + (size_t)L * DM, h, h,
                SEQ, DM, DI);
        }
    }

    rmsnorm_kernel<<<SEQ, 256, 0, stream>>>(h, norm_f, hn, full ? hn_b : nullptr,
                                            nullptr, nullptr, nullptr);
    if (full) {
        gemm_256<0><<<dim3(SEQ / 256, NVOCP / 256), 1024, 98304, stream>>>(
            hn_b, lm_wT, out, nullptr, nullptr, nullptr, nullptr, SEQ, NVOC, DM);
    } else {
        gemm_f32<0><<<dim3(NVOC / 64, SEQ / 64), dim3(16, 16), 0, stream>>>(
            hn, DM, lm_w, nullptr, nullptr, out, SEQ, NVOC, DM);
    }
}